// Round 3
// baseline (583.249 us; speedup 1.0000x reference)
//
#include <hip/hip_runtime.h>

#define B 8
#define N 2048
#define KF 256
#define DF 64
#define LOG2E 1.44269504088896340736f
#define IC 8
#define ICH (N / IC)   // 256

__device__ __forceinline__ float lrelu(float x) { return fmaxf(x, 0.2f * x); }
__device__ __forceinline__ float eluf(float x) { return x > 0.f ? x : expm1f(x); }

// ---- A: Wh = h @ W, fused f1/f2. W staged in LDS; h rows read as
// wave-uniform scalars (no tid in address -> s_load). 16 rows/block. ----
__global__ __launch_bounds__(256) void k_wh(const float* __restrict__ h,
                                            const float* __restrict__ W,
                                            const float* __restrict__ a,
                                            float* __restrict__ Wh,
                                            float* __restrict__ f1,
                                            float* __restrict__ f2) {
    __shared__ float lw[KF * DF];   // 64 KB
    int t = threadIdx.x;
    int lane = t & 63, wv = t >> 6;
    long rowbase = (long)blockIdx.x * 16;

    const float4* W4 = (const float4*)W;
    float4* lw4 = (float4*)lw;
    for (int idx = t; idx < KF * DF / 4; idx += 256) lw4[idx] = W4[idx];
    __syncthreads();

    long r0 = rowbase + wv * 4;
    const float* hrow = h + r0 * KF;
    float acc0 = 0.f, acc1 = 0.f, acc2 = 0.f, acc3 = 0.f;
    #pragma unroll 32
    for (int k = 0; k < KF; k++) {
        float wk = lw[k * DF + lane];
        acc0 = fmaf(hrow[k], wk, acc0);
        acc1 = fmaf(hrow[KF + k], wk, acc1);
        acc2 = fmaf(hrow[2 * KF + k], wk, acc2);
        acc3 = fmaf(hrow[3 * KF + k], wk, acc3);
    }

    float a1 = a[lane], a2 = a[DF + lane];
    float accs[4] = {acc0, acc1, acc2, acc3};   // fully unrolled below
    #pragma unroll
    for (int r = 0; r < 4; r++) {
        float av = accs[r];
        Wh[(r0 + r) * DF + lane] = av;
        float s1 = av * a1;
        float s2 = av * a2;
        #pragma unroll
        for (int off = 32; off; off >>= 1) {
            s1 += __shfl_xor(s1, off, 64);
            s2 += __shfl_xor(s2, off, 64);
        }
        if (lane == 0) { f1[r0 + r] = s1; f2[r0 + r] = s2; }
    }
}

// ---- per-batch max of f1 (8 blocks, tree reduce, no atomics) ----
__global__ __launch_bounds__(256) void k_colmax(const float* __restrict__ f1,
                                                float* __restrict__ f1max) {
    __shared__ float red[256];
    int t = threadIdx.x, b = blockIdx.x;
    float m = -1e30f;
    #pragma unroll
    for (int k = 0; k < N / 256; k++) m = fmaxf(m, f1[b * N + k * 256 + t]);
    red[t] = m;
    __syncthreads();
    for (int s = 128; s; s >>= 1) {
        if (t < s) red[t] = fmaxf(red[t], red[t + s]);
        __syncthreads();
    }
    if (t == 0) f1max[b] = red[0];
}

// ---- D: partial denom slabs (no atomics): dpart[ic][b*N+j] ----
__global__ __launch_bounds__(256) void k_denom(const float* __restrict__ f1,
                                               const float* __restrict__ f2,
                                               const float* __restrict__ f1max,
                                               float* __restrict__ dpart) {
    __shared__ float lf1[ICH];
    int t = threadIdx.x;
    int b = blockIdx.z, ic = blockIdx.y;
    int j = blockIdx.x * 256 + t;
    lf1[t] = f1[b * N + ic * ICH + t];
    __syncthreads();
    float f2j = f2[b * N + j];
    float mL = lrelu(f1max[b] + f2j) * LOG2E;
    float s = 0.f;
    for (int ii = 0; ii < ICH; ii++) {
        float l = lrelu(lf1[ii] + f2j);
        s += exp2f(fmaf(l, LOG2E, -mL));
    }
    dpart[((long)ic * B + b) * N + j] = s;
}

// ---- pack per-j constants: {f2, m*LOG2E, 1/denom, 0} ----
__global__ void k_pack(const float* __restrict__ f2,
                       const float* __restrict__ dpart,
                       const float* __restrict__ f1max,
                       float4* __restrict__ col) {
    int idx = blockIdx.x * 256 + threadIdx.x;   // 16384
    int b = idx >> 11;
    float d = 0.f;
    #pragma unroll
    for (int ic = 0; ic < IC; ic++) d += dpart[((long)ic * B + b) * N + (idx & (N - 1))];
    float f2j = f2[idx];
    float mL = lrelu(f1max[b] + f2j) * LOG2E;
    col[idx] = make_float4(f2j, mL, 1.0f / d, 0.f);
}

// ---- E: main contraction. 2 threads/row x 32 feats; j chunked by NC.
// Accumulators are NAMED float4 locals (c0..c7) — the float4 acc[8] array
// form was demoted to scratch by the compiler (VGPR_Count=36, 17 GB L2
// scratch RMW = the whole 475 us). Do not re-introduce an array here. ----
#define ACC_STEP(k)                     \
    {                                   \
        float4 v = wr[k];               \
        c##k.x = fmaf(w, v.x, c##k.x);  \
        c##k.y = fmaf(w, v.y, c##k.y);  \
        c##k.z = fmaf(w, v.z, c##k.z);  \
        c##k.w = fmaf(w, v.w, c##k.w);  \
    }

template <int NC, bool DIRECT>
__global__ __launch_bounds__(256) void k_main(const float* __restrict__ Wh,
                                              const float* __restrict__ f1,
                                              const float4* __restrict__ col,
                                              float* __restrict__ outp) {
    int t = threadIdx.x;
    int i2 = t >> 1, qq = t & 1;
    int c = blockIdx.x, iblk = blockIdx.y, b = blockIdx.z;
    long row = (long)b * N + (long)iblk * 128 + i2;
    float f1i = f1[row];
    float4 c0 = make_float4(0.f, 0.f, 0.f, 0.f), c1 = c0, c2 = c0, c3 = c0,
           c4 = c0, c5 = c0, c6 = c0, c7 = c0;

    const int CH = N / NC;
    long jbase = (long)b * N + (long)c * CH;
    const float4* wh4 = (const float4*)Wh + jbase * 16 + qq * 8;

    for (int jj = 0; jj < CH; jj++) {
        float4 cv = col[jbase + jj];                  // wave-uniform -> s_load
        float t0 = f1i + cv.x;
        float l = fmaxf(t0, 0.2f * t0);
        float w = exp2f(fmaf(l, LOG2E, -cv.y)) * cv.z;
        const float4* wr = wh4 + (long)jj * 16;
        ACC_STEP(0) ACC_STEP(1) ACC_STEP(2) ACC_STEP(3)
        ACC_STEP(4) ACC_STEP(5) ACC_STEP(6) ACC_STEP(7)
    }

    if (DIRECT) {
        float4* o4 = (float4*)outp + row * 16 + qq * 8;
        #define STORE_E(k)                                              \
            {                                                           \
                float4 v = c##k;                                        \
                v.x = eluf(v.x); v.y = eluf(v.y);                       \
                v.z = eluf(v.z); v.w = eluf(v.w);                       \
                o4[k] = v;                                              \
            }
        STORE_E(0) STORE_E(1) STORE_E(2) STORE_E(3)
        STORE_E(4) STORE_E(5) STORE_E(6) STORE_E(7)
    } else {
        float4* p4 = (float4*)outp + ((long)c * (B * N) + row) * 16 + qq * 8;
        p4[0] = c0; p4[1] = c1; p4[2] = c2; p4[3] = c3;
        p4[4] = c4; p4[5] = c5; p4[6] = c6; p4[7] = c7;
    }
}

// ---- F: reduce NC partials + ELU ----
template <int NC>
__global__ void k_reduce(const float4* __restrict__ part, float4* __restrict__ out) {
    long idx = (long)blockIdx.x * 256 + threadIdx.x;   // 262144 float4s
    const long stride = (long)B * N * 16;
    float4 s = part[idx];
    #pragma unroll
    for (int c = 1; c < NC; c++) {
        float4 v = part[(long)c * stride + idx];
        s.x += v.x; s.y += v.y; s.z += v.z; s.w += v.w;
    }
    s.x = eluf(s.x); s.y = eluf(s.y); s.z = eluf(s.z); s.w = eluf(s.w);
    out[idx] = s;
}

extern "C" void kernel_launch(void* const* d_in, const int* in_sizes, int n_in,
                              void* d_out, int out_size, void* d_ws, size_t ws_size,
                              hipStream_t stream) {
    const float* h = (const float*)d_in[0];
    const float* W = (const float*)d_in[1];
    const float* a = (const float*)d_in[2];
    float* out = (float*)d_out;

    char* ws = (char*)d_ws;
    const size_t NB = (size_t)B * N;          // 16384 rows
    size_t off = 0;
    float* Wh    = (float*)(ws + off); off += NB * DF * sizeof(float);     // 4 MB
    float* f1    = (float*)(ws + off); off += NB * sizeof(float);
    float* f2    = (float*)(ws + off); off += NB * sizeof(float);
    float* dpart = (float*)(ws + off); off += (size_t)IC * NB * sizeof(float); // 512 KB
    float4* col  = (float4*)(ws + off); off += NB * sizeof(float4);
    float* f1max = (float*)(ws + off); off += 64;
    off = (off + 255) & ~(size_t)255;
    float* part  = (float*)(ws + off);
    const size_t chunk_bytes = NB * DF * sizeof(float);                    // 4 MB

    int NC = 1;
    if (off + 8 * chunk_bytes <= ws_size) NC = 8;
    else if (off + 4 * chunk_bytes <= ws_size) NC = 4;
    else if (off + 2 * chunk_bytes <= ws_size) NC = 2;

    k_wh<<<NB / 16, 256, 0, stream>>>(h, W, a, Wh, f1, f2);
    k_colmax<<<B, 256, 0, stream>>>(f1, f1max);
    k_denom<<<dim3(N / 256, IC, B), 256, 0, stream>>>(f1, f2, f1max, dpart);
    k_pack<<<NB / 256, 256, 0, stream>>>(f2, dpart, f1max, col);

    if (NC == 8) {
        k_main<8, false><<<dim3(8, N / 128, B), 256, 0, stream>>>(Wh, f1, col, part);
        k_reduce<8><<<(NB * DF / 4) / 256, 256, 0, stream>>>((const float4*)part, (float4*)out);
    } else if (NC == 4) {
        k_main<4, false><<<dim3(4, N / 128, B), 256, 0, stream>>>(Wh, f1, col, part);
        k_reduce<4><<<(NB * DF / 4) / 256, 256, 0, stream>>>((const float4*)part, (float4*)out);
    } else if (NC == 2) {
        k_main<2, false><<<dim3(2, N / 128, B), 256, 0, stream>>>(Wh, f1, col, part);
        k_reduce<2><<<(NB * DF / 4) / 256, 256, 0, stream>>>((const float4*)part, (float4*)out);
    } else {
        k_main<1, true><<<dim3(1, N / 128, B), 256, 0, stream>>>(Wh, f1, col, out);
    }
}

// Round 4
// 159.455 us; speedup vs baseline: 3.6578x; 3.6578x over previous
//
#include <hip/hip_runtime.h>

#define B 8
#define N 2048
#define KF 256
#define DF 64
#define LOG2E 1.44269504088896340736f
#define IC 8
#define ICH (N / IC)   // 256

typedef __attribute__((ext_vector_type(8))) short short8;   // 8 bf16 (4 VGPRs)
typedef __attribute__((ext_vector_type(4))) float float4v;  // MFMA C/D frag

__device__ __forceinline__ float fexp2(float x) {
#if __has_builtin(__builtin_amdgcn_exp2f)
    return __builtin_amdgcn_exp2f(x);
#else
    return exp2f(x);
#endif
}
__device__ __forceinline__ float lrelu(float x) { return fmaxf(x, 0.2f * x); }
__device__ __forceinline__ float eluf(float x) {
    return x > 0.f ? x : fexp2(x * LOG2E) - 1.0f;
}
// float -> bf16 bits, round-half-up (error <= 0.5 ulp; inputs here are finite)
__device__ __forceinline__ short bf16r(float x) {
    unsigned u = __float_as_uint(x);
    return (short)((u + 0x8000u) >> 16);
}

// ---- A: Wh = h @ W, fused f1/f2, emits TRANSPOSED bf16 WhT[b][d][j].
// W staged in LDS; h rows read wave-uniform (s_load). 16 rows/block. ----
__global__ __launch_bounds__(256) void k_wh(const float* __restrict__ h,
                                            const float* __restrict__ W,
                                            const float* __restrict__ a,
                                            short* __restrict__ WhT,
                                            float* __restrict__ f1,
                                            float* __restrict__ f2) {
    __shared__ float lw[KF * DF];   // 64 KB
    int t = threadIdx.x;
    int lane = t & 63, wv = t >> 6;
    long rowbase = (long)blockIdx.x * 16;

    const float4* W4 = (const float4*)W;
    float4* lw4 = (float4*)lw;
    for (int idx = t; idx < KF * DF / 4; idx += 256) lw4[idx] = W4[idx];
    __syncthreads();

    long r0 = rowbase + wv * 4;
    const float* hrow = h + r0 * KF;
    float acc0 = 0.f, acc1 = 0.f, acc2 = 0.f, acc3 = 0.f;
    #pragma unroll 32
    for (int k = 0; k < KF; k++) {
        float wk = lw[k * DF + lane];
        acc0 = fmaf(hrow[k], wk, acc0);
        acc1 = fmaf(hrow[KF + k], wk, acc1);
        acc2 = fmaf(hrow[2 * KF + k], wk, acc2);
        acc3 = fmaf(hrow[3 * KF + k], wk, acc3);
    }

    // transposed bf16 store: WhT[b][d=lane][i0..i0+3]
    int b = (int)(r0 >> 11);
    int il = (int)(r0 & (N - 1));
    short4 pk = make_short4(bf16r(acc0), bf16r(acc1), bf16r(acc2), bf16r(acc3));
    *(short4*)(WhT + ((long)b * DF + lane) * N + il) = pk;

    float a1 = a[lane], a2 = a[DF + lane];
    float accs[4] = {acc0, acc1, acc2, acc3};
    #pragma unroll
    for (int r = 0; r < 4; r++) {
        float s1 = accs[r] * a1;
        float s2 = accs[r] * a2;
        #pragma unroll
        for (int off = 32; off; off >>= 1) {
            s1 += __shfl_xor(s1, off, 64);
            s2 += __shfl_xor(s2, off, 64);
        }
        if (lane == 0) { f1[r0 + r] = s1; f2[r0 + r] = s2; }
    }
}

// ---- per-batch max of f1 (8 blocks, tree reduce, no atomics) ----
__global__ __launch_bounds__(256) void k_colmax(const float* __restrict__ f1,
                                                float* __restrict__ f1max) {
    __shared__ float red[256];
    int t = threadIdx.x, b = blockIdx.x;
    float m = -1e30f;
    #pragma unroll
    for (int k = 0; k < N / 256; k++) m = fmaxf(m, f1[b * N + k * 256 + t]);
    red[t] = m;
    __syncthreads();
    for (int s = 128; s; s >>= 1) {
        if (t < s) red[t] = fmaxf(red[t], red[t + s]);
        __syncthreads();
    }
    if (t == 0) f1max[b] = red[0];
}

// ---- D: partial denom slabs (no atomics): dpart[ic][b*N+j] ----
__global__ __launch_bounds__(256) void k_denom(const float* __restrict__ f1,
                                               const float* __restrict__ f2,
                                               const float* __restrict__ f1max,
                                               float* __restrict__ dpart) {
    __shared__ float lf1[ICH];
    int t = threadIdx.x;
    int b = blockIdx.z, ic = blockIdx.y;
    int j = blockIdx.x * 256 + t;
    lf1[t] = f1[b * N + ic * ICH + t];
    __syncthreads();
    float f2j = f2[b * N + j];
    float mL = lrelu(f1max[b] + f2j) * LOG2E;
    float s = 0.f;
    for (int ii = 0; ii < ICH; ii++) {
        float l = lrelu(lf1[ii] + f2j);
        s += fexp2(fmaf(l, LOG2E, -mL));
    }
    dpart[((long)ic * B + b) * N + j] = s;
}

// ---- pack per-j constants: col2[j] = {f2j*LOG2E, 2^(-mL)/den} ----
__global__ void k_pack(const float* __restrict__ f2,
                       const float* __restrict__ dpart,
                       const float* __restrict__ f1max,
                       float2* __restrict__ col2) {
    int idx = blockIdx.x * 256 + threadIdx.x;   // 16384
    int b = idx >> 11;
    float d = 0.f;
    #pragma unroll
    for (int ic = 0; ic < IC; ic++) d += dpart[((long)ic * B + b) * N + (idx & (N - 1))];
    float f2j = f2[idx];
    float mL = lrelu(f1max[b] + f2j) * LOG2E;
    float s = fexp2(-mL) / d;
    col2[idx] = make_float2(f2j * LOG2E, s);
}

// ---- E: flash-style MFMA contraction O = P @ Wh.
// Wave computes 16 i-rows x 64 d via 4x mfma_f32_16x16x32_bf16 per 32-j step.
// A-frag P built on the fly from f1 + col2 (6 VALU/entry); B-frags are
// contiguous 16B loads from WhT[b][d][j]. No LDS. ----
template <int NC, bool DIRECT>
__global__ __launch_bounds__(256) void k_attn(const short* __restrict__ WhT,
                                              const float* __restrict__ f1,
                                              const float2* __restrict__ col2,
                                              float* __restrict__ outp) {
    int t = threadIdx.x;
    int wv = t >> 6, lane = t & 63;
    int c = blockIdx.x, it = blockIdx.y, b = blockIdx.z;
    int n15 = lane & 15;        // A: m-row | B: n-col | D: col
    int q = lane >> 4;          // k-group

    int i0 = it * 64 + wv * 16;
    float f1L = f1[b * N + i0 + n15] * LOG2E;

    const int CH = N / NC;
    int j0base = c * CH;
    const short* wt = WhT + (long)b * DF * N + (long)n15 * N;

    float4v acc0 = {0.f, 0.f, 0.f, 0.f}, acc1 = acc0, acc2 = acc0, acc3 = acc0;

    for (int js = 0; js < CH; js += 32) {
        int j0 = j0base + js;
        // A-frag: 8 P entries, k = q*8 + idx
        const float4* cp4 = (const float4*)(col2 + (long)b * N + j0 + q * 8);
        float4 p01 = cp4[0], p23 = cp4[1], p45 = cp4[2], p67 = cp4[3];
        short8 af;
        #define PENT(F2L, S, DI)                          \
            {                                             \
                float t0 = f1L + (F2L);                   \
                float l2 = fmaxf(t0, 0.2f * t0);          \
                float w = fexp2(l2) * (S);                \
                af[DI] = bf16r(w);                        \
            }
        PENT(p01.x, p01.y, 0) PENT(p01.z, p01.w, 1)
        PENT(p23.x, p23.y, 2) PENT(p23.z, p23.w, 3)
        PENT(p45.x, p45.y, 4) PENT(p45.z, p45.w, 5)
        PENT(p67.x, p67.y, 6) PENT(p67.z, p67.w, 7)
        #undef PENT

        // B-frags: WhT[d = nb*16 + n15][j0 + q*8 .. +8) — 16B contiguous
        const short* bp = wt + j0 + q * 8;
        short8 b0 = *(const short8*)(bp);
        short8 b1 = *(const short8*)(bp + 16 * N);
        short8 b2 = *(const short8*)(bp + 32 * N);
        short8 b3 = *(const short8*)(bp + 48 * N);

        acc0 = __builtin_amdgcn_mfma_f32_16x16x32_bf16(af, b0, acc0, 0, 0, 0);
        acc1 = __builtin_amdgcn_mfma_f32_16x16x32_bf16(af, b1, acc1, 0, 0, 0);
        acc2 = __builtin_amdgcn_mfma_f32_16x16x32_bf16(af, b2, acc2, 0, 0, 0);
        acc3 = __builtin_amdgcn_mfma_f32_16x16x32_bf16(af, b3, acc3, 0, 0, 0);
    }

    // D layout: col = n15 (d within 16), row = q*4 + r (i within 16)
    if (DIRECT) {
        float* ob = outp + ((long)b * N + i0 + q * 4) * DF + n15;
        #pragma unroll
        for (int r = 0; r < 4; r++) {
            ob[r * DF + 0]  = eluf(acc0[r]);
            ob[r * DF + 16] = eluf(acc1[r]);
            ob[r * DF + 32] = eluf(acc2[r]);
            ob[r * DF + 48] = eluf(acc3[r]);
        }
    } else {
        float* pb = outp + ((long)c * (B * N) + (long)b * N + i0 + q * 4) * DF + n15;
        #pragma unroll
        for (int r = 0; r < 4; r++) {
            pb[r * DF + 0]  = acc0[r];
            pb[r * DF + 16] = acc1[r];
            pb[r * DF + 32] = acc2[r];
            pb[r * DF + 48] = acc3[r];
        }
    }
}

// ---- F: reduce NC partials + ELU ----
template <int NC>
__global__ void k_reduce(const float4* __restrict__ part, float4* __restrict__ out) {
    long idx = (long)blockIdx.x * 256 + threadIdx.x;   // 262144 float4s
    const long stride = (long)B * N * 16;
    float4 s = part[idx];
    #pragma unroll
    for (int c = 1; c < NC; c++) {
        float4 v = part[(long)c * stride + idx];
        s.x += v.x; s.y += v.y; s.z += v.z; s.w += v.w;
    }
    s.x = eluf(s.x); s.y = eluf(s.y); s.z = eluf(s.z); s.w = eluf(s.w);
    out[idx] = s;
}

extern "C" void kernel_launch(void* const* d_in, const int* in_sizes, int n_in,
                              void* d_out, int out_size, void* d_ws, size_t ws_size,
                              hipStream_t stream) {
    const float* h = (const float*)d_in[0];
    const float* W = (const float*)d_in[1];
    const float* a = (const float*)d_in[2];
    float* out = (float*)d_out;

    char* ws = (char*)d_ws;
    const size_t NB = (size_t)B * N;          // 16384 rows
    size_t off = 0;
    short* WhT   = (short*)(ws + off); off += NB * DF * sizeof(short);     // 2 MB
    float* f1    = (float*)(ws + off); off += NB * sizeof(float);
    float* f2    = (float*)(ws + off); off += NB * sizeof(float);
    float* dpart = (float*)(ws + off); off += (size_t)IC * NB * sizeof(float); // 512 KB
    float2* col2 = (float2*)(ws + off); off += NB * sizeof(float2);
    float* f1max = (float*)(ws + off); off += 64;
    off = (off + 255) & ~(size_t)255;
    float* part  = (float*)(ws + off);
    const size_t chunk_bytes = NB * DF * sizeof(float);                    // 4 MB

    int NC = 1;
    if (off + 4 * chunk_bytes <= ws_size) NC = 4;
    else if (off + 2 * chunk_bytes <= ws_size) NC = 2;

    k_wh<<<NB / 16, 256, 0, stream>>>(h, W, a, WhT, f1, f2);
    k_colmax<<<B, 256, 0, stream>>>(f1, f1max);
    k_denom<<<dim3(N / 256, IC, B), 256, 0, stream>>>(f1, f2, f1max, dpart);
    k_pack<<<NB / 256, 256, 0, stream>>>(f2, dpart, f1max, col2);

    if (NC == 4) {
        k_attn<4, false><<<dim3(4, N / 64, B), 256, 0, stream>>>(WhT, f1, col2, part);
        k_reduce<4><<<(NB * DF / 4) / 256, 256, 0, stream>>>((const float4*)part, (float4*)out);
    } else if (NC == 2) {
        k_attn<2, false><<<dim3(2, N / 64, B), 256, 0, stream>>>(WhT, f1, col2, part);
        k_reduce<2><<<(NB * DF / 4) / 256, 256, 0, stream>>>((const float4*)part, (float4*)out);
    } else {
        k_attn<1, true><<<dim3(1, N / 64, B), 256, 0, stream>>>(WhT, f1, col2, out);
    }
}

// Round 5
// 128.216 us; speedup vs baseline: 4.5489x; 1.2436x over previous
//
#include <hip/hip_runtime.h>

#define B 8
#define N 2048
#define KF 256
#define DF 64
#define LOG2E 1.44269504088896340736f
#define IC 8
#define ICH (N / IC)   // 256

typedef __attribute__((ext_vector_type(8))) short short8;   // 8 bf16 (4 VGPRs)
typedef __attribute__((ext_vector_type(4))) float float4v;  // MFMA C/D frag

__device__ __forceinline__ float fexp2(float x) {
#if __has_builtin(__builtin_amdgcn_exp2f)
    return __builtin_amdgcn_exp2f(x);
#else
    return exp2f(x);
#endif
}
__device__ __forceinline__ float lrelu(float x) { return fmaxf(x, 0.2f * x); }
__device__ __forceinline__ float eluf(float x) {
    return x > 0.f ? x : fexp2(x * LOG2E) - 1.0f;
}
// float -> bf16 bits, round-half-up
__device__ __forceinline__ short bf16r(float x) {
    unsigned u = __float_as_uint(x);
    return (short)((u + 0x8000u) >> 16);
}

// ---- P: transpose W -> bf16 WTg[n][k] (blocks 0..63); block 64 computes
// v1 = W@a1, v2 = W@a2 in fp32 (f1 = h@v1 identity kills the Wh->f1 dep). ----
__global__ __launch_bounds__(256) void k_v(const float* __restrict__ W,
                                           const float* __restrict__ a,
                                           short* __restrict__ WTg,
                                           float* __restrict__ v12) {
    int t = threadIdx.x;
    if (blockIdx.x < 64) {
        int idx = blockIdx.x * 256 + t;       // 16384 = KF*DF
        int k = idx >> 6, n = idx & 63;
        WTg[n * KF + k] = bf16r(W[idx]);
    } else {
        float s1 = 0.f, s2 = 0.f;             // t indexes k (256 threads)
        for (int d = 0; d < DF; d++) {
            float w = W[t * DF + d];
            s1 = fmaf(w, a[d], s1);
            s2 = fmaf(w, a[DF + d], s2);
        }
        v12[t] = s1;
        v12[KF + t] = s2;
    }
}

// ---- A: Wh = h@W via MFMA, LDS-free; fused f1/f2 via h.v1 / h.v2.
// Wave = 16 rows; A-frags from 2xfloat4 h loads (read-once); B-frags are
// 16B contiguous loads from WTg (L1-resident). Emits transposed bf16 WhT. ----
__global__ __launch_bounds__(256) void k_wh(const float* __restrict__ h,
                                            const short* __restrict__ WTg,
                                            const float* __restrict__ v12,
                                            short* __restrict__ WhT,
                                            float* __restrict__ f1,
                                            float* __restrict__ f2) {
    int t = threadIdx.x;
    int wv = t >> 6, lane = t & 63;
    int n15 = lane & 15, q = lane >> 4;
    long i0 = (long)blockIdx.x * 64 + wv * 16;
    const float* hr = h + (i0 + n15) * KF;
    const short* bp0 = WTg + n15 * KF;

    float4v acc0 = {0.f, 0.f, 0.f, 0.f}, acc1 = acc0, acc2 = acc0, acc3 = acc0;
    float p1 = 0.f, p2 = 0.f;

    #pragma unroll
    for (int kq = 0; kq < 8; kq++) {
        int k0 = kq * 32 + q * 8;
        float4 a0 = *(const float4*)(hr + k0);
        float4 a1 = *(const float4*)(hr + k0 + 4);
        float4 u0 = *(const float4*)(v12 + k0);
        float4 u1 = *(const float4*)(v12 + k0 + 4);
        float4 x0 = *(const float4*)(v12 + KF + k0);
        float4 x1 = *(const float4*)(v12 + KF + k0 + 4);
        p1 = fmaf(a0.x, u0.x, fmaf(a0.y, u0.y, fmaf(a0.z, u0.z, fmaf(a0.w, u0.w, p1))));
        p1 = fmaf(a1.x, u1.x, fmaf(a1.y, u1.y, fmaf(a1.z, u1.z, fmaf(a1.w, u1.w, p1))));
        p2 = fmaf(a0.x, x0.x, fmaf(a0.y, x0.y, fmaf(a0.z, x0.z, fmaf(a0.w, x0.w, p2))));
        p2 = fmaf(a1.x, x1.x, fmaf(a1.y, x1.y, fmaf(a1.z, x1.z, fmaf(a1.w, x1.w, p2))));

        short8 af = { bf16r(a0.x), bf16r(a0.y), bf16r(a0.z), bf16r(a0.w),
                      bf16r(a1.x), bf16r(a1.y), bf16r(a1.z), bf16r(a1.w) };
        const short* bp = bp0 + k0;
        short8 b0 = *(const short8*)(bp);
        short8 b1 = *(const short8*)(bp + 16 * KF);
        short8 b2 = *(const short8*)(bp + 32 * KF);
        short8 b3 = *(const short8*)(bp + 48 * KF);

        acc0 = __builtin_amdgcn_mfma_f32_16x16x32_bf16(af, b0, acc0, 0, 0, 0);
        acc1 = __builtin_amdgcn_mfma_f32_16x16x32_bf16(af, b1, acc1, 0, 0, 0);
        acc2 = __builtin_amdgcn_mfma_f32_16x16x32_bf16(af, b2, acc2, 0, 0, 0);
        acc3 = __builtin_amdgcn_mfma_f32_16x16x32_bf16(af, b3, acc3, 0, 0, 0);
    }

    int b = (int)(i0 >> 11);
    int il = (int)(i0 & (N - 1));
    // D layout: lane holds rows i = il + q*4 + r (4 consecutive), col d = n15+16nb
    // -> exactly a short4 store into WhT[b][d][i]
    #define STORE_WT(nb, A)                                                     \
        {                                                                       \
            short4 pk = make_short4(bf16r(A[0]), bf16r(A[1]),                   \
                                    bf16r(A[2]), bf16r(A[3]));                  \
            *(short4*)(WhT + ((long)b * DF + n15 + 16 * nb) * N + il + q * 4) = pk; \
        }
    STORE_WT(0, acc0) STORE_WT(1, acc1) STORE_WT(2, acc2) STORE_WT(3, acc3)
    #undef STORE_WT

    p1 += __shfl_xor(p1, 16, 64); p1 += __shfl_xor(p1, 32, 64);
    p2 += __shfl_xor(p2, 16, 64); p2 += __shfl_xor(p2, 32, 64);
    if (q == 0) {
        f1[i0 + n15] = p1;
        f2[i0 + n15] = p2;
    }
}

// ---- D: partial denom slabs (no max needed: e bounded ~20, fp32 safe) ----
__global__ __launch_bounds__(256) void k_denom(const float* __restrict__ f1,
                                               const float* __restrict__ f2,
                                               float* __restrict__ dpart) {
    __shared__ float lf1[ICH];
    int t = threadIdx.x;
    int b = blockIdx.z, ic = blockIdx.y;
    int j = blockIdx.x * 256 + t;
    lf1[t] = f1[b * N + ic * ICH + t];
    __syncthreads();
    float f2j = f2[b * N + j];
    float s = 0.f;
    for (int ii = 0; ii < ICH; ii++) {
        float e = (lf1[ii] + f2j) * LOG2E;
        s += fexp2(fmaxf(e, 0.2f * e));
    }
    dpart[((long)ic * B + b) * N + j] = s;
}

// ---- pack per-j constants: col2[j] = {f2j*LOG2E, 1/den} ----
__global__ void k_pack(const float* __restrict__ f2,
                       const float* __restrict__ dpart,
                       float2* __restrict__ col2) {
    int idx = blockIdx.x * 256 + threadIdx.x;   // 16384
    int b = idx >> 11;
    float d = 0.f;
    #pragma unroll
    for (int ic = 0; ic < IC; ic++) d += dpart[((long)ic * B + b) * N + (idx & (N - 1))];
    col2[idx] = make_float2(f2[idx] * LOG2E, 1.0f / d);
}

// ---- E: flash-style MFMA contraction O = P @ Wh (unchanged from R4). ----
template <int NC, bool DIRECT>
__global__ __launch_bounds__(256) void k_attn(const short* __restrict__ WhT,
                                              const float* __restrict__ f1,
                                              const float2* __restrict__ col2,
                                              float* __restrict__ outp) {
    int t = threadIdx.x;
    int wv = t >> 6, lane = t & 63;
    int c = blockIdx.x, it = blockIdx.y, b = blockIdx.z;
    int n15 = lane & 15;
    int q = lane >> 4;

    int i0 = it * 64 + wv * 16;
    float f1L = f1[b * N + i0 + n15] * LOG2E;

    const int CH = N / NC;
    int j0base = c * CH;
    const short* wt = WhT + (long)b * DF * N + (long)n15 * N;

    float4v acc0 = {0.f, 0.f, 0.f, 0.f}, acc1 = acc0, acc2 = acc0, acc3 = acc0;

    for (int js = 0; js < CH; js += 32) {
        int j0 = j0base + js;
        const float4* cp4 = (const float4*)(col2 + (long)b * N + j0 + q * 8);
        float4 p01 = cp4[0], p23 = cp4[1], p45 = cp4[2], p67 = cp4[3];
        short8 af;
        #define PENT(F2L, S, DI)                          \
            {                                             \
                float t0 = f1L + (F2L);                   \
                float l2 = fmaxf(t0, 0.2f * t0);          \
                float w = fexp2(l2) * (S);                \
                af[DI] = bf16r(w);                        \
            }
        PENT(p01.x, p01.y, 0) PENT(p01.z, p01.w, 1)
        PENT(p23.x, p23.y, 2) PENT(p23.z, p23.w, 3)
        PENT(p45.x, p45.y, 4) PENT(p45.z, p45.w, 5)
        PENT(p67.x, p67.y, 6) PENT(p67.z, p67.w, 7)
        #undef PENT

        const short* bp = wt + j0 + q * 8;
        short8 b0 = *(const short8*)(bp);
        short8 b1 = *(const short8*)(bp + 16 * N);
        short8 b2 = *(const short8*)(bp + 32 * N);
        short8 b3 = *(const short8*)(bp + 48 * N);

        acc0 = __builtin_amdgcn_mfma_f32_16x16x32_bf16(af, b0, acc0, 0, 0, 0);
        acc1 = __builtin_amdgcn_mfma_f32_16x16x32_bf16(af, b1, acc1, 0, 0, 0);
        acc2 = __builtin_amdgcn_mfma_f32_16x16x32_bf16(af, b2, acc2, 0, 0, 0);
        acc3 = __builtin_amdgcn_mfma_f32_16x16x32_bf16(af, b3, acc3, 0, 0, 0);
    }

    if (DIRECT) {
        float* ob = outp + ((long)b * N + i0 + q * 4) * DF + n15;
        #pragma unroll
        for (int r = 0; r < 4; r++) {
            ob[r * DF + 0]  = eluf(acc0[r]);
            ob[r * DF + 16] = eluf(acc1[r]);
            ob[r * DF + 32] = eluf(acc2[r]);
            ob[r * DF + 48] = eluf(acc3[r]);
        }
    } else {
        float* pb = outp + ((long)c * (B * N) + (long)b * N + i0 + q * 4) * DF + n15;
        #pragma unroll
        for (int r = 0; r < 4; r++) {
            pb[r * DF + 0]  = acc0[r];
            pb[r * DF + 16] = acc1[r];
            pb[r * DF + 32] = acc2[r];
            pb[r * DF + 48] = acc3[r];
        }
    }
}

// ---- F: reduce NC partials + ELU ----
template <int NC>
__global__ void k_reduce(const float4* __restrict__ part, float4* __restrict__ out) {
    long idx = (long)blockIdx.x * 256 + threadIdx.x;   // 262144 float4s
    const long stride = (long)B * N * 16;
    float4 s = part[idx];
    #pragma unroll
    for (int c = 1; c < NC; c++) {
        float4 v = part[(long)c * stride + idx];
        s.x += v.x; s.y += v.y; s.z += v.z; s.w += v.w;
    }
    s.x = eluf(s.x); s.y = eluf(s.y); s.z = eluf(s.z); s.w = eluf(s.w);
    out[idx] = s;
}

extern "C" void kernel_launch(void* const* d_in, const int* in_sizes, int n_in,
                              void* d_out, int out_size, void* d_ws, size_t ws_size,
                              hipStream_t stream) {
    const float* h = (const float*)d_in[0];
    const float* W = (const float*)d_in[1];
    const float* a = (const float*)d_in[2];
    float* out = (float*)d_out;

    char* ws = (char*)d_ws;
    const size_t NB = (size_t)B * N;          // 16384 rows
    size_t off = 0;
    short* WTg   = (short*)(ws + off); off += (size_t)KF * DF * sizeof(short); // 32 KB
    float* v12   = (float*)(ws + off); off += 2 * KF * sizeof(float);          // 2 KB
    short* WhT   = (short*)(ws + off); off += NB * DF * sizeof(short);         // 2 MB
    float* f1    = (float*)(ws + off); off += NB * sizeof(float);
    float* f2    = (float*)(ws + off); off += NB * sizeof(float);
    float* dpart = (float*)(ws + off); off += (size_t)IC * NB * sizeof(float); // 512 KB
    float2* col2 = (float2*)(ws + off); off += NB * sizeof(float2);
    off = (off + 255) & ~(size_t)255;
    float* part  = (float*)(ws + off);
    const size_t chunk_bytes = NB * DF * sizeof(float);                        // 4 MB

    int NC = 1;
    if (off + 4 * chunk_bytes <= ws_size) NC = 4;
    else if (off + 2 * chunk_bytes <= ws_size) NC = 2;

    k_v<<<65, 256, 0, stream>>>(W, a, WTg, v12);
    k_wh<<<NB / 64, 256, 0, stream>>>(h, WTg, v12, WhT, f1, f2);
    k_denom<<<dim3(N / 256, IC, B), 256, 0, stream>>>(f1, f2, dpart);
    k_pack<<<NB / 256, 256, 0, stream>>>(f2, dpart, col2);

    if (NC == 4) {
        k_attn<4, false><<<dim3(4, N / 64, B), 256, 0, stream>>>(WhT, f1, col2, part);
        k_reduce<4><<<(NB * DF / 4) / 256, 256, 0, stream>>>((const float4*)part, (float4*)out);
    } else if (NC == 2) {
        k_attn<2, false><<<dim3(2, N / 64, B), 256, 0, stream>>>(WhT, f1, col2, part);
        k_reduce<2><<<(NB * DF / 4) / 256, 256, 0, stream>>>((const float4*)part, (float4*)out);
    } else {
        k_attn<1, true><<<dim3(1, N / 64, B), 256, 0, stream>>>(WhT, f1, col2, out);
    }
}

// Round 6
// 125.925 us; speedup vs baseline: 4.6317x; 1.0182x over previous
//
#include <hip/hip_runtime.h>

#define B 8
#define N 2048
#define KF 256
#define DF 64
#define LOG2E 1.44269504088896340736f
#define IC 8
#define ICH (N / IC)   // 256

typedef __attribute__((ext_vector_type(8))) short short8;   // 8 bf16 (4 VGPRs)
typedef __attribute__((ext_vector_type(4))) float float4v;  // MFMA C/D frag

__device__ __forceinline__ float fexp2(float x) {
#if __has_builtin(__builtin_amdgcn_exp2f)
    return __builtin_amdgcn_exp2f(x);
#else
    return exp2f(x);
#endif
}
__device__ __forceinline__ float eluf(float x) {
    return x > 0.f ? x : fexp2(x * LOG2E) - 1.0f;
}
// float -> bf16 bits, round-half-up
__device__ __forceinline__ short bf16r(float x) {
    unsigned u = __float_as_uint(x);
    return (short)((u + 0x8000u) >> 16);
}

// ---- P: transpose W -> bf16 WTg[n][k]; block 64: v1 = W@a1, v2 = W@a2. ----
__global__ __launch_bounds__(256) void k_v(const float* __restrict__ W,
                                           const float* __restrict__ a,
                                           short* __restrict__ WTg,
                                           float* __restrict__ v12) {
    int t = threadIdx.x;
    if (blockIdx.x < 64) {
        int idx = blockIdx.x * 256 + t;       // 16384 = KF*DF
        int k = idx >> 6, n = idx & 63;
        WTg[n * KF + k] = bf16r(W[idx]);
    } else {
        float s1 = 0.f, s2 = 0.f;             // t indexes k
        for (int d = 0; d < DF; d++) {
            float w = W[t * DF + d];
            s1 = fmaf(w, a[d], s1);
            s2 = fmaf(w, a[DF + d], s2);
        }
        v12[t] = s1;
        v12[KF + t] = s2;
    }
}

// ---- A: Wh = h@W via MFMA, K-split 4 ways across the block's waves
// (wave wv covers k in [wv*64, wv*64+64)) -> 4096 waves instead of 1024.
// fp32 C + f1/f2 partials reduced via LDS; emits transposed bf16 WhT. ----
__global__ __launch_bounds__(256) void k_wh(const float* __restrict__ h,
                                            const short* __restrict__ WTg,
                                            const float* __restrict__ v12,
                                            short* __restrict__ WhT,
                                            float* __restrict__ f1,
                                            float* __restrict__ f2) {
    __shared__ float lred[4 * 16 * DF];   // 16 KB: [wv][i][d]
    __shared__ float lp[2][4][16];
    int t = threadIdx.x;
    int wv = t >> 6, lane = t & 63;
    int n15 = lane & 15, q = lane >> 4;
    long i0 = (long)blockIdx.x * 16;
    const float* hr = h + (i0 + n15) * KF + wv * 64;
    const short* bp0 = WTg + n15 * KF + wv * 64;

    float4v acc0 = {0.f, 0.f, 0.f, 0.f}, acc1 = acc0, acc2 = acc0, acc3 = acc0;
    float p1 = 0.f, p2 = 0.f;

    #pragma unroll
    for (int s = 0; s < 2; s++) {
        int k0 = s * 32 + q * 8;
        int kg = wv * 64 + k0;
        float4 a0 = *(const float4*)(hr + k0);
        float4 a1 = *(const float4*)(hr + k0 + 4);
        float4 u0 = *(const float4*)(v12 + kg);
        float4 u1 = *(const float4*)(v12 + kg + 4);
        float4 x0 = *(const float4*)(v12 + KF + kg);
        float4 x1 = *(const float4*)(v12 + KF + kg + 4);
        p1 = fmaf(a0.x, u0.x, fmaf(a0.y, u0.y, fmaf(a0.z, u0.z, fmaf(a0.w, u0.w, p1))));
        p1 = fmaf(a1.x, u1.x, fmaf(a1.y, u1.y, fmaf(a1.z, u1.z, fmaf(a1.w, u1.w, p1))));
        p2 = fmaf(a0.x, x0.x, fmaf(a0.y, x0.y, fmaf(a0.z, x0.z, fmaf(a0.w, x0.w, p2))));
        p2 = fmaf(a1.x, x1.x, fmaf(a1.y, x1.y, fmaf(a1.z, x1.z, fmaf(a1.w, x1.w, p2))));

        short8 af = { bf16r(a0.x), bf16r(a0.y), bf16r(a0.z), bf16r(a0.w),
                      bf16r(a1.x), bf16r(a1.y), bf16r(a1.z), bf16r(a1.w) };
        const short* bp = bp0 + k0;
        short8 b0 = *(const short8*)(bp);
        short8 b1 = *(const short8*)(bp + 16 * KF);
        short8 b2 = *(const short8*)(bp + 32 * KF);
        short8 b3 = *(const short8*)(bp + 48 * KF);

        acc0 = __builtin_amdgcn_mfma_f32_16x16x32_bf16(af, b0, acc0, 0, 0, 0);
        acc1 = __builtin_amdgcn_mfma_f32_16x16x32_bf16(af, b1, acc1, 0, 0, 0);
        acc2 = __builtin_amdgcn_mfma_f32_16x16x32_bf16(af, b2, acc2, 0, 0, 0);
        acc3 = __builtin_amdgcn_mfma_f32_16x16x32_bf16(af, b3, acc3, 0, 0, 0);
    }

    // stash C frags: D layout row=q*4+r, col=nb*16+n15
    #define STASH(nb, A)                                                 \
        {                                                                \
            _Pragma("unroll")                                            \
            for (int r = 0; r < 4; r++)                                  \
                lred[wv * 1024 + (q * 4 + r) * DF + nb * 16 + n15] = A[r]; \
        }
    STASH(0, acc0) STASH(1, acc1) STASH(2, acc2) STASH(3, acc3)
    #undef STASH

    p1 += __shfl_xor(p1, 16, 64); p1 += __shfl_xor(p1, 32, 64);
    p2 += __shfl_xor(p2, 16, 64); p2 += __shfl_xor(p2, 32, 64);
    if (q == 0) { lp[0][wv][n15] = p1; lp[1][wv][n15] = p2; }
    __syncthreads();

    // reduce over 4 waves; thread t: d = t&63, i-group ig = t>>6 (4 i's)
    int d = t & 63, ig = t >> 6;
    int b = (int)(i0 >> 11);
    int il = (int)(i0 & (N - 1));
    float s0 = 0.f, s1 = 0.f, s2 = 0.f, s3 = 0.f;
    #pragma unroll
    for (int w = 0; w < 4; w++) {
        const float* lr = lred + w * 1024 + (ig * 4) * DF + d;
        s0 += lr[0]; s1 += lr[DF]; s2 += lr[2 * DF]; s3 += lr[3 * DF];
    }
    short4 pk = make_short4(bf16r(s0), bf16r(s1), bf16r(s2), bf16r(s3));
    *(short4*)(WhT + ((long)b * DF + d) * N + il + ig * 4) = pk;

    if (t < 16) {
        float v = lp[0][0][t] + lp[0][1][t] + lp[0][2][t] + lp[0][3][t];
        f1[i0 + t] = v;
    } else if (t < 32) {
        int tt = t - 16;
        float v = lp[1][0][tt] + lp[1][1][tt] + lp[1][2][tt] + lp[1][3][tt];
        f2[i0 + tt] = v;
    }
}

// ---- D: partial denom slabs (no max needed: e bounded, fp32 safe) ----
__global__ __launch_bounds__(256) void k_denom(const float* __restrict__ f1,
                                               const float* __restrict__ f2,
                                               float* __restrict__ dpart) {
    __shared__ float lf1[ICH];
    int t = threadIdx.x;
    int b = blockIdx.z, ic = blockIdx.y;
    int j = blockIdx.x * 256 + t;
    lf1[t] = f1[b * N + ic * ICH + t];
    __syncthreads();
    float f2j = f2[b * N + j];
    float s = 0.f;
    for (int ii = 0; ii < ICH; ii++) {
        float e = (lf1[ii] + f2j) * LOG2E;
        s += fexp2(fmaxf(e, 0.2f * e));
    }
    dpart[((long)ic * B + b) * N + j] = s;
}

// ---- pack per-j constants: col2[j] = {f2j*LOG2E, 1/den} ----
__global__ void k_pack(const float* __restrict__ f2,
                       const float* __restrict__ dpart,
                       float2* __restrict__ col2) {
    int idx = blockIdx.x * 256 + threadIdx.x;   // 16384
    int b = idx >> 11;
    float d = 0.f;
    #pragma unroll
    for (int ic = 0; ic < IC; ic++) d += dpart[((long)ic * B + b) * N + (idx & (N - 1))];
    col2[idx] = make_float2(f2[idx] * LOG2E, 1.0f / d);
}

// ---- E: flash-style MFMA contraction O = P @ Wh.
// Block = 8 waves sharing one 16-row i-tile; wave wv covers j in
// [wv*256, wv*256+256). 8192 waves total (8/SIMD). C-frags reduced via LDS,
// ELU applied, stored directly — no partial round-trip, no k_reduce. ----
__global__ __launch_bounds__(512) void k_attn(const short* __restrict__ WhT,
                                              const float* __restrict__ f1,
                                              const float2* __restrict__ col2,
                                              float* __restrict__ out) {
    __shared__ float lred[8 * 16 * DF];   // 32 KB: [wv][i][d]
    int t = threadIdx.x;
    int wv = t >> 6, lane = t & 63;
    int n15 = lane & 15, q = lane >> 4;
    int it = blockIdx.x, b = blockIdx.y;
    int i0 = it * 16;

    float f1L = f1[b * N + i0 + n15] * LOG2E;
    const short* wt = WhT + (long)b * DF * N + (long)n15 * N;
    int j0base = wv * 256;

    float4v acc0 = {0.f, 0.f, 0.f, 0.f}, acc1 = acc0, acc2 = acc0, acc3 = acc0;

    #pragma unroll 2
    for (int js = 0; js < 256; js += 32) {
        int j0 = j0base + js;
        const float4* cp4 = (const float4*)(col2 + (long)b * N + j0 + q * 8);
        float4 p01 = cp4[0], p23 = cp4[1], p45 = cp4[2], p67 = cp4[3];
        short8 af;
        #define PENT(F2L, S, DI)                          \
            {                                             \
                float t0 = f1L + (F2L);                   \
                float l2 = fmaxf(t0, 0.2f * t0);          \
                float w = fexp2(l2) * (S);                \
                af[DI] = bf16r(w);                        \
            }
        PENT(p01.x, p01.y, 0) PENT(p01.z, p01.w, 1)
        PENT(p23.x, p23.y, 2) PENT(p23.z, p23.w, 3)
        PENT(p45.x, p45.y, 4) PENT(p45.z, p45.w, 5)
        PENT(p67.x, p67.y, 6) PENT(p67.z, p67.w, 7)
        #undef PENT

        const short* bp = wt + j0 + q * 8;
        short8 b0 = *(const short8*)(bp);
        short8 b1 = *(const short8*)(bp + 16 * N);
        short8 b2 = *(const short8*)(bp + 32 * N);
        short8 b3 = *(const short8*)(bp + 48 * N);

        acc0 = __builtin_amdgcn_mfma_f32_16x16x32_bf16(af, b0, acc0, 0, 0, 0);
        acc1 = __builtin_amdgcn_mfma_f32_16x16x32_bf16(af, b1, acc1, 0, 0, 0);
        acc2 = __builtin_amdgcn_mfma_f32_16x16x32_bf16(af, b2, acc2, 0, 0, 0);
        acc3 = __builtin_amdgcn_mfma_f32_16x16x32_bf16(af, b3, acc3, 0, 0, 0);
    }

    #define STASH(nb, A)                                                 \
        {                                                                \
            _Pragma("unroll")                                            \
            for (int r = 0; r < 4; r++)                                  \
                lred[wv * 1024 + (q * 4 + r) * DF + nb * 16 + n15] = A[r]; \
        }
    STASH(0, acc0) STASH(1, acc1) STASH(2, acc2) STASH(3, acc3)
    #undef STASH
    __syncthreads();

    // 512 threads x 2 consecutive outputs each (o = t*2, same i, d even)
    int o = t * 2;
    int i = o >> 6, d = o & 63;
    float s0 = 0.f, s1 = 0.f;
    #pragma unroll
    for (int w = 0; w < 8; w++) {
        s0 += lred[w * 1024 + o];
        s1 += lred[w * 1024 + o + 1];
    }
    float2 st = make_float2(eluf(s0), eluf(s1));
    *(float2*)(out + ((long)b * N + i0 + i) * DF + d) = st;
}

extern "C" void kernel_launch(void* const* d_in, const int* in_sizes, int n_in,
                              void* d_out, int out_size, void* d_ws, size_t ws_size,
                              hipStream_t stream) {
    const float* h = (const float*)d_in[0];
    const float* W = (const float*)d_in[1];
    const float* a = (const float*)d_in[2];
    float* out = (float*)d_out;

    char* ws = (char*)d_ws;
    const size_t NB = (size_t)B * N;          // 16384 rows
    size_t off = 0;
    short* WTg   = (short*)(ws + off); off += (size_t)KF * DF * sizeof(short); // 32 KB
    float* v12   = (float*)(ws + off); off += 2 * KF * sizeof(float);          // 2 KB
    short* WhT   = (short*)(ws + off); off += NB * DF * sizeof(short);         // 2 MB
    float* f1    = (float*)(ws + off); off += NB * sizeof(float);
    float* f2    = (float*)(ws + off); off += NB * sizeof(float);
    float* dpart = (float*)(ws + off); off += (size_t)IC * NB * sizeof(float); // 512 KB
    float2* col2 = (float2*)(ws + off); off += NB * sizeof(float2);
    (void)off; (void)ws_size;

    k_v<<<65, 256, 0, stream>>>(W, a, WTg, v12);
    k_wh<<<NB / 16, 256, 0, stream>>>(h, WTg, v12, WhT, f1, f2);
    k_denom<<<dim3(N / 256, IC, B), 256, 0, stream>>>(f1, f2, dpart);
    k_pack<<<NB / 256, 256, 0, stream>>>(f2, dpart, col2);
    k_attn<<<dim3(N / 16, B), 512, 0, stream>>>(WhT, f1, col2, out);
}

// Round 7
// 119.514 us; speedup vs baseline: 4.8802x; 1.0536x over previous
//
#include <hip/hip_runtime.h>

#define B 8
#define N 2048
#define KF 256
#define DF 64
#define LOG2E 1.44269504088896340736f
#define IC 8
#define ICH (N / IC)   // 256

typedef __attribute__((ext_vector_type(8))) short short8;   // 8 bf16 (4 VGPRs)
typedef __attribute__((ext_vector_type(4))) float float4v;  // MFMA C/D frag

__device__ __forceinline__ float fexp2(float x) {
#if __has_builtin(__builtin_amdgcn_exp2f)
    return __builtin_amdgcn_exp2f(x);
#else
    return exp2f(x);
#endif
}
__device__ __forceinline__ float eluf(float x) {
    return x > 0.f ? x : fexp2(x * LOG2E) - 1.0f;
}
// float -> bf16 bits, round-half-up
__device__ __forceinline__ short bf16r(float x) {
    unsigned u = __float_as_uint(x);
    return (short)((u + 0x8000u) >> 16);
}

// ---- P: transpose W -> bf16 WTg[n][k]; block 64: v1 = W@a1, v2 = W@a2. ----
__global__ __launch_bounds__(256) void k_v(const float* __restrict__ W,
                                           const float* __restrict__ a,
                                           short* __restrict__ WTg,
                                           float* __restrict__ v12) {
    int t = threadIdx.x;
    if (blockIdx.x < 64) {
        int idx = blockIdx.x * 256 + t;       // 16384 = KF*DF
        int k = idx >> 6, n = idx & 63;
        WTg[n * KF + k] = bf16r(W[idx]);
    } else {
        float s1 = 0.f, s2 = 0.f;             // t indexes k
        for (int d = 0; d < DF; d++) {
            float w = W[t * DF + d];
            s1 = fmaf(w, a[d], s1);
            s2 = fmaf(w, a[DF + d], s2);
        }
        v12[t] = s1;
        v12[KF + t] = s2;
    }
}

// ---- A: Wh = h@W via MFMA, K-split 4 ways across the block's waves.
// Emits WhT in CHUNK-MAJOR layout: WhT[b][j>>8][d][j&255] so each 256-j
// chunk (64 d x 256 j bf16 = 32 KB) is contiguous for k_attn's staging. ----
__global__ __launch_bounds__(256) void k_wh(const float* __restrict__ h,
                                            const short* __restrict__ WTg,
                                            const float* __restrict__ v12,
                                            short* __restrict__ WhT,
                                            float* __restrict__ f1,
                                            float* __restrict__ f2) {
    __shared__ float lred[4 * 16 * DF];   // 16 KB: [wv][i][d]
    __shared__ float lp[2][4][16];
    int t = threadIdx.x;
    int wv = t >> 6, lane = t & 63;
    int n15 = lane & 15, q = lane >> 4;
    long i0 = (long)blockIdx.x * 16;
    const float* hr = h + (i0 + n15) * KF + wv * 64;
    const short* bp0 = WTg + n15 * KF + wv * 64;

    float4v acc0 = {0.f, 0.f, 0.f, 0.f}, acc1 = acc0, acc2 = acc0, acc3 = acc0;
    float p1 = 0.f, p2 = 0.f;

    #pragma unroll
    for (int s = 0; s < 2; s++) {
        int k0 = s * 32 + q * 8;
        int kg = wv * 64 + k0;
        float4 a0 = *(const float4*)(hr + k0);
        float4 a1 = *(const float4*)(hr + k0 + 4);
        float4 u0 = *(const float4*)(v12 + kg);
        float4 u1 = *(const float4*)(v12 + kg + 4);
        float4 x0 = *(const float4*)(v12 + KF + kg);
        float4 x1 = *(const float4*)(v12 + KF + kg + 4);
        p1 = fmaf(a0.x, u0.x, fmaf(a0.y, u0.y, fmaf(a0.z, u0.z, fmaf(a0.w, u0.w, p1))));
        p1 = fmaf(a1.x, u1.x, fmaf(a1.y, u1.y, fmaf(a1.z, u1.z, fmaf(a1.w, u1.w, p1))));
        p2 = fmaf(a0.x, x0.x, fmaf(a0.y, x0.y, fmaf(a0.z, x0.z, fmaf(a0.w, x0.w, p2))));
        p2 = fmaf(a1.x, x1.x, fmaf(a1.y, x1.y, fmaf(a1.z, x1.z, fmaf(a1.w, x1.w, p2))));

        short8 af = { bf16r(a0.x), bf16r(a0.y), bf16r(a0.z), bf16r(a0.w),
                      bf16r(a1.x), bf16r(a1.y), bf16r(a1.z), bf16r(a1.w) };
        const short* bp = bp0 + k0;
        short8 b0 = *(const short8*)(bp);
        short8 b1 = *(const short8*)(bp + 16 * KF);
        short8 b2 = *(const short8*)(bp + 32 * KF);
        short8 b3 = *(const short8*)(bp + 48 * KF);

        acc0 = __builtin_amdgcn_mfma_f32_16x16x32_bf16(af, b0, acc0, 0, 0, 0);
        acc1 = __builtin_amdgcn_mfma_f32_16x16x32_bf16(af, b1, acc1, 0, 0, 0);
        acc2 = __builtin_amdgcn_mfma_f32_16x16x32_bf16(af, b2, acc2, 0, 0, 0);
        acc3 = __builtin_amdgcn_mfma_f32_16x16x32_bf16(af, b3, acc3, 0, 0, 0);
    }

    // stash C frags: D layout row=q*4+r, col=nb*16+n15
    #define STASH(nb, A)                                                 \
        {                                                                \
            _Pragma("unroll")                                            \
            for (int r = 0; r < 4; r++)                                  \
                lred[wv * 1024 + (q * 4 + r) * DF + nb * 16 + n15] = A[r]; \
        }
    STASH(0, acc0) STASH(1, acc1) STASH(2, acc2) STASH(3, acc3)
    #undef STASH

    p1 += __shfl_xor(p1, 16, 64); p1 += __shfl_xor(p1, 32, 64);
    p2 += __shfl_xor(p2, 16, 64); p2 += __shfl_xor(p2, 32, 64);
    if (q == 0) { lp[0][wv][n15] = p1; lp[1][wv][n15] = p2; }
    __syncthreads();

    // reduce over 4 waves; thread t: d = t&63, i-group ig = t>>6 (4 i's)
    int d = t & 63, ig = t >> 6;
    int bb = (int)(i0 >> 11);
    int il = (int)(i0 & (N - 1));
    float s0 = 0.f, s1 = 0.f, s2 = 0.f, s3 = 0.f;
    #pragma unroll
    for (int w = 0; w < 4; w++) {
        const float* lr = lred + w * 1024 + (ig * 4) * DF + d;
        s0 += lr[0]; s1 += lr[DF]; s2 += lr[2 * DF]; s3 += lr[3 * DF];
    }
    short4 pk = make_short4(bf16r(s0), bf16r(s1), bf16r(s2), bf16r(s3));
    int jj = il + ig * 4;   // batch-local j index of these 4 Wh rows
    *(short4*)(WhT + (((long)bb * 8 + (jj >> 8)) * 64 + d) * 256 + (jj & 255)) = pk;

    if (t < 16) {
        float v = lp[0][0][t] + lp[0][1][t] + lp[0][2][t] + lp[0][3][t];
        f1[i0 + t] = v;
    } else if (t < 32) {
        int tt = t - 16;
        float v = lp[1][0][tt] + lp[1][1][tt] + lp[1][2][tt] + lp[1][3][tt];
        f2[i0 + tt] = v;
    }
}

// ---- D: partial denom slabs (no max needed: e bounded, fp32 safe) ----
__global__ __launch_bounds__(256) void k_denom(const float* __restrict__ f1,
                                               const float* __restrict__ f2,
                                               float* __restrict__ dpart) {
    __shared__ float lf1[ICH];
    int t = threadIdx.x;
    int b = blockIdx.z, ic = blockIdx.y;
    int j = blockIdx.x * 256 + t;
    lf1[t] = f1[b * N + ic * ICH + t];
    __syncthreads();
    float f2j = f2[b * N + j];
    float s = 0.f;
    for (int ii = 0; ii < ICH; ii++) {
        float e = (lf1[ii] + f2j) * LOG2E;
        s += fexp2(fmaxf(e, 0.2f * e));
    }
    dpart[((long)ic * B + b) * N + j] = s;
}

// ---- pack per-j constants: col2[j] = {f2j*LOG2E, 1/den} ----
__global__ void k_pack(const float* __restrict__ f2,
                       const float* __restrict__ dpart,
                       float2* __restrict__ col2) {
    int idx = blockIdx.x * 256 + threadIdx.x;   // 16384
    int b = idx >> 11;
    float d = 0.f;
    #pragma unroll
    for (int ic = 0; ic < IC; ic++) d += dpart[((long)ic * B + b) * N + (idx & (N - 1))];
    col2[idx] = make_float2(f2[idx] * LOG2E, 1.0f / d);
}

// ---- E: O = P @ Wh, LDS-staged GEMM. Block = 4 waves, i-tile 64 (wave
// owns 16 rows end-to-end -> no partials). Loop over 8 j-chunks: stage the
// contiguous 32 KB WhT chunk + 2 KB col2 into LDS with coalesced bulk
// loads (high MLP -> kills the per-step L3 latency chain of R5/R6), then
// 8 MFMA k-steps from LDS. Rows padded to 33 uint4 (528 B): +4 banks/row
// -> 2-way alias on ds_read_b128 (free per m136). ----
__global__ __launch_bounds__(256) void k_attn(const short* __restrict__ WhT,
                                              const float* __restrict__ f1,
                                              const float2* __restrict__ col2,
                                              float* __restrict__ out) {
    __shared__ uint4 ls[64][33];     // 33.8 KB staged Wh chunk, padded rows
    __shared__ float2 lc[256];       // 2 KB staged col2 chunk
    int t = threadIdx.x;
    int wv = t >> 6, lane = t & 63;
    int n15 = lane & 15, q = lane >> 4;
    int it = blockIdx.x, b = blockIdx.y;
    int i0 = it * 64 + wv * 16;      // wave-private 16 i-rows

    float f1L = f1[b * N + i0 + n15] * LOG2E;
    const uint4* wsrc = (const uint4*)WhT + (long)b * 8 * 2048;  // 8 chunks x 2048 uint4
    const float2* csrc = col2 + b * N;
    const short* lsS = (const short*)ls;

    float4v acc0 = {0.f, 0.f, 0.f, 0.f}, acc1 = acc0, acc2 = acc0, acc3 = acc0;

    for (int c = 0; c < 8; c++) {
        const uint4* gsrc = wsrc + c * 2048;
        #pragma unroll
        for (int k = 0; k < 8; k++) {
            int u = k * 256 + t;                 // 2048 x 16 B
            ls[u >> 5][u & 31] = gsrc[u];
        }
        lc[t] = csrc[c * 256 + t];
        __syncthreads();

        #pragma unroll
        for (int js = 0; js < 8; js++) {
            const float4* cp4 = (const float4*)lc + js * 16 + q * 4;
            float4 p01 = cp4[0], p23 = cp4[1], p45 = cp4[2], p67 = cp4[3];
            short8 af;
            #define PENT(F2L, S, DI)                          \
                {                                             \
                    float t0 = f1L + (F2L);                   \
                    float l2 = fmaxf(t0, 0.2f * t0);          \
                    float w = fexp2(l2) * (S);                \
                    af[DI] = bf16r(w);                        \
                }
            PENT(p01.x, p01.y, 0) PENT(p01.z, p01.w, 1)
            PENT(p23.x, p23.y, 2) PENT(p23.z, p23.w, 3)
            PENT(p45.x, p45.y, 4) PENT(p45.z, p45.w, 5)
            PENT(p67.x, p67.y, 6) PENT(p67.z, p67.w, 7)
            #undef PENT

            const short* bp = lsS + js * 32 + q * 8;   // + d*264 per row
            short8 b0 = *(const short8*)(bp + (n15 +  0) * 264);
            short8 b1 = *(const short8*)(bp + (n15 + 16) * 264);
            short8 b2 = *(const short8*)(bp + (n15 + 32) * 264);
            short8 b3 = *(const short8*)(bp + (n15 + 48) * 264);

            acc0 = __builtin_amdgcn_mfma_f32_16x16x32_bf16(af, b0, acc0, 0, 0, 0);
            acc1 = __builtin_amdgcn_mfma_f32_16x16x32_bf16(af, b1, acc1, 0, 0, 0);
            acc2 = __builtin_amdgcn_mfma_f32_16x16x32_bf16(af, b2, acc2, 0, 0, 0);
            acc3 = __builtin_amdgcn_mfma_f32_16x16x32_bf16(af, b3, acc3, 0, 0, 0);
        }
        __syncthreads();
    }

    // D layout: col = n15 (d within 16), row = q*4 + r (i within 16)
    float* ob = out + ((long)b * N + i0 + q * 4) * DF + n15;
    #pragma unroll
    for (int r = 0; r < 4; r++) {
        ob[r * DF + 0]  = eluf(acc0[r]);
        ob[r * DF + 16] = eluf(acc1[r]);
        ob[r * DF + 32] = eluf(acc2[r]);
        ob[r * DF + 48] = eluf(acc3[r]);
    }
}

extern "C" void kernel_launch(void* const* d_in, const int* in_sizes, int n_in,
                              void* d_out, int out_size, void* d_ws, size_t ws_size,
                              hipStream_t stream) {
    const float* h = (const float*)d_in[0];
    const float* W = (const float*)d_in[1];
    const float* a = (const float*)d_in[2];
    float* out = (float*)d_out;

    char* ws = (char*)d_ws;
    const size_t NB = (size_t)B * N;          // 16384 rows
    size_t off = 0;
    short* WTg   = (short*)(ws + off); off += (size_t)KF * DF * sizeof(short); // 32 KB
    float* v12   = (float*)(ws + off); off += 2 * KF * sizeof(float);          // 2 KB
    short* WhT   = (short*)(ws + off); off += NB * DF * sizeof(short);         // 2 MB
    float* f1    = (float*)(ws + off); off += NB * sizeof(float);
    float* f2    = (float*)(ws + off); off += NB * sizeof(float);
    float* dpart = (float*)(ws + off); off += (size_t)IC * NB * sizeof(float); // 512 KB
    float2* col2 = (float2*)(ws + off); off += NB * sizeof(float2);
    (void)off; (void)ws_size;

    k_v<<<65, 256, 0, stream>>>(W, a, WTg, v12);
    k_wh<<<NB / 16, 256, 0, stream>>>(h, WTg, v12, WhT, f1, f2);
    k_denom<<<dim3(N / 256, IC, B), 256, 0, stream>>>(f1, f2, dpart);
    k_pack<<<NB / 256, 256, 0, stream>>>(f2, dpart, col2);
    k_attn<<<dim3(N / 64, B), 256, 0, stream>>>(WhT, f1, col2, out);
}

// Round 8
// 105.103 us; speedup vs baseline: 5.5493x; 1.1371x over previous
//
#include <hip/hip_runtime.h>

#define B 8
#define N 2048
#define KF 256
#define DF 64
#define LOG2E 1.44269504088896340736f
#define IC 8
#define ICH (N / IC)   // 256

typedef __attribute__((ext_vector_type(8))) short short8;   // 8 bf16 (4 VGPRs)
typedef __attribute__((ext_vector_type(4))) float float4v;  // MFMA C/D frag

__device__ __forceinline__ float fexp2(float x) {
#if __has_builtin(__builtin_amdgcn_exp2f)
    return __builtin_amdgcn_exp2f(x);
#else
    return exp2f(x);
#endif
}
__device__ __forceinline__ float flog2(float x) {
#if __has_builtin(__builtin_amdgcn_logf)
    return __builtin_amdgcn_logf(x);
#else
    return log2f(x);
#endif
}
__device__ __forceinline__ float eluf(float x) {
    return x > 0.f ? x : fexp2(x * LOG2E) - 1.0f;
}
// float -> bf16 bits, round-half-up
__device__ __forceinline__ short bf16r(float x) {
    unsigned u = __float_as_uint(x);
    return (short)((u + 0x8000u) >> 16);
}

// ---- P: transpose W -> bf16 WTg[n][k]; block 64: v1 = W@a1, v2 = W@a2. ----
__global__ __launch_bounds__(256) void k_v(const float* __restrict__ W,
                                           const float* __restrict__ a,
                                           short* __restrict__ WTg,
                                           float* __restrict__ v12) {
    int t = threadIdx.x;
    if (blockIdx.x < 64) {
        int idx = blockIdx.x * 256 + t;       // 16384 = KF*DF
        int k = idx >> 6, n = idx & 63;
        WTg[n * KF + k] = bf16r(W[idx]);
    } else {
        float s1 = 0.f, s2 = 0.f;             // t indexes k
        for (int d = 0; d < DF; d++) {
            float w = W[t * DF + d];
            s1 = fmaf(w, a[d], s1);
            s2 = fmaf(w, a[DF + d], s2);
        }
        v12[t] = s1;
        v12[KF + t] = s2;
    }
}

// ---- A: Wh = h@W via MFMA, K-split 4 ways across the block's waves.
// Emits WhT chunk-major: WhT[b][j>>8][d][j&255] (32 KB contiguous chunks). ----
__global__ __launch_bounds__(256) void k_wh(const float* __restrict__ h,
                                            const short* __restrict__ WTg,
                                            const float* __restrict__ v12,
                                            short* __restrict__ WhT,
                                            float* __restrict__ f1,
                                            float* __restrict__ f2) {
    __shared__ float lred[4 * 16 * DF];   // 16 KB: [wv][i][d]
    __shared__ float lp[2][4][16];
    int t = threadIdx.x;
    int wv = t >> 6, lane = t & 63;
    int n15 = lane & 15, q = lane >> 4;
    long i0 = (long)blockIdx.x * 16;
    const float* hr = h + (i0 + n15) * KF + wv * 64;
    const short* bp0 = WTg + n15 * KF + wv * 64;

    float4v acc0 = {0.f, 0.f, 0.f, 0.f}, acc1 = acc0, acc2 = acc0, acc3 = acc0;
    float p1 = 0.f, p2 = 0.f;

    #pragma unroll
    for (int s = 0; s < 2; s++) {
        int k0 = s * 32 + q * 8;
        int kg = wv * 64 + k0;
        float4 a0 = *(const float4*)(hr + k0);
        float4 a1 = *(const float4*)(hr + k0 + 4);
        float4 u0 = *(const float4*)(v12 + kg);
        float4 u1 = *(const float4*)(v12 + kg + 4);
        float4 x0 = *(const float4*)(v12 + KF + kg);
        float4 x1 = *(const float4*)(v12 + KF + kg + 4);
        p1 = fmaf(a0.x, u0.x, fmaf(a0.y, u0.y, fmaf(a0.z, u0.z, fmaf(a0.w, u0.w, p1))));
        p1 = fmaf(a1.x, u1.x, fmaf(a1.y, u1.y, fmaf(a1.z, u1.z, fmaf(a1.w, u1.w, p1))));
        p2 = fmaf(a0.x, x0.x, fmaf(a0.y, x0.y, fmaf(a0.z, x0.z, fmaf(a0.w, x0.w, p2))));
        p2 = fmaf(a1.x, x1.x, fmaf(a1.y, x1.y, fmaf(a1.z, x1.z, fmaf(a1.w, x1.w, p2))));

        short8 af = { bf16r(a0.x), bf16r(a0.y), bf16r(a0.z), bf16r(a0.w),
                      bf16r(a1.x), bf16r(a1.y), bf16r(a1.z), bf16r(a1.w) };
        const short* bp = bp0 + k0;
        short8 b0 = *(const short8*)(bp);
        short8 b1 = *(const short8*)(bp + 16 * KF);
        short8 b2 = *(const short8*)(bp + 32 * KF);
        short8 b3 = *(const short8*)(bp + 48 * KF);

        acc0 = __builtin_amdgcn_mfma_f32_16x16x32_bf16(af, b0, acc0, 0, 0, 0);
        acc1 = __builtin_amdgcn_mfma_f32_16x16x32_bf16(af, b1, acc1, 0, 0, 0);
        acc2 = __builtin_amdgcn_mfma_f32_16x16x32_bf16(af, b2, acc2, 0, 0, 0);
        acc3 = __builtin_amdgcn_mfma_f32_16x16x32_bf16(af, b3, acc3, 0, 0, 0);
    }

    #define STASH(nb, A)                                                 \
        {                                                                \
            _Pragma("unroll")                                            \
            for (int r = 0; r < 4; r++)                                  \
                lred[wv * 1024 + (q * 4 + r) * DF + nb * 16 + n15] = A[r]; \
        }
    STASH(0, acc0) STASH(1, acc1) STASH(2, acc2) STASH(3, acc3)
    #undef STASH

    p1 += __shfl_xor(p1, 16, 64); p1 += __shfl_xor(p1, 32, 64);
    p2 += __shfl_xor(p2, 16, 64); p2 += __shfl_xor(p2, 32, 64);
    if (q == 0) { lp[0][wv][n15] = p1; lp[1][wv][n15] = p2; }
    __syncthreads();

    int d = t & 63, ig = t >> 6;
    int bb = (int)(i0 >> 11);
    int il = (int)(i0 & (N - 1));
    float s0 = 0.f, s1 = 0.f, s2 = 0.f, s3 = 0.f;
    #pragma unroll
    for (int w = 0; w < 4; w++) {
        const float* lr = lred + w * 1024 + (ig * 4) * DF + d;
        s0 += lr[0]; s1 += lr[DF]; s2 += lr[2 * DF]; s3 += lr[3 * DF];
    }
    short4 pk = make_short4(bf16r(s0), bf16r(s1), bf16r(s2), bf16r(s3));
    int jj = il + ig * 4;
    *(short4*)(WhT + (((long)bb * 8 + (jj >> 8)) * 64 + d) * 256 + (jj & 255)) = pk;

    if (t < 16) {
        float v = lp[0][0][t] + lp[0][1][t] + lp[0][2][t] + lp[0][3][t];
        f1[i0 + t] = v;
    } else if (t < 32) {
        int tt = t - 16;
        float v = lp[1][0][tt] + lp[1][1][tt] + lp[1][2][tt] + lp[1][3][tt];
        f2[i0 + tt] = v;
    }
}

// ---- D: partial denom slabs (no max needed: e bounded, fp32 safe) ----
__global__ __launch_bounds__(256) void k_denom(const float* __restrict__ f1,
                                               const float* __restrict__ f2,
                                               float* __restrict__ dpart) {
    __shared__ float lf1[ICH];
    int t = threadIdx.x;
    int b = blockIdx.z, ic = blockIdx.y;
    int j = blockIdx.x * 256 + t;
    lf1[t] = f1[b * N + ic * ICH + t];
    __syncthreads();
    float f2j = f2[b * N + j];
    float s = 0.f;
    for (int ii = 0; ii < ICH; ii++) {
        float e = (lf1[ii] + f2j) * LOG2E;
        s += fexp2(fmaxf(e, 0.2f * e));
    }
    dpart[((long)ic * B + b) * N + j] = s;
}

// ---- E: O = P @ Wh, LDS GEMM with register-prefetch pipeline + fused pack.
// Block = 4 waves, i-tile 64 (wave owns 16 rows end-to-end). Per chunk c:
// chunk c+1's global loads (WhT 32KB + f2/dpart) are issued into REGISTERS
// before computing chunk c from LDS, so latency hides under compute; only
// the drain + 8 ds_writes + 2 barriers are exposed. lc[j]={f2L, -log2 den}
// (pack fused here; w = exp2(l2 + ls2) saves the *S mul per entry). ----
__global__ __launch_bounds__(256) void k_attn(const short* __restrict__ WhT,
                                              const float* __restrict__ f1,
                                              const float* __restrict__ f2,
                                              const float* __restrict__ dpart,
                                              float* __restrict__ out) {
    __shared__ uint4 ls[64][33];     // 33.8 KB, padded rows (2-way alias: free)
    __shared__ float2 lc[2][256];    // 4 KB, double-buffered
    int t = threadIdx.x;
    int wv = t >> 6, lane = t & 63;
    int n15 = lane & 15, q = lane >> 4;
    int it = blockIdx.x, b = blockIdx.y;
    int i0 = it * 64 + wv * 16;

    float f1L = f1[b * N + i0 + n15] * LOG2E;
    const uint4* wsrc = (const uint4*)WhT + (long)b * 8 * 2048;
    const float* f2b = f2 + b * N;
    const float* dpb = dpart + b * N;   // + ic*16384 per slice

    uint4 r0, r1, r2, r3, r4, r5, r6, r7;
    float pf2, pd0, pd1, pd2, pd3, pd4, pd5, pd6, pd7;

    #define LOADC(cc) {                                     \
        const uint4* gp = wsrc + (cc) * 2048;               \
        r0 = gp[t];        r1 = gp[256 + t];                \
        r2 = gp[512 + t];  r3 = gp[768 + t];                \
        r4 = gp[1024 + t]; r5 = gp[1280 + t];               \
        r6 = gp[1536 + t]; r7 = gp[1792 + t];               \
    }
    #define LOADP(cc) {                                     \
        int jb = (cc) * 256 + t;                            \
        pf2 = f2b[jb];                                      \
        pd0 = dpb[jb];               pd1 = dpb[16384 + jb]; \
        pd2 = dpb[2 * 16384 + jb];   pd3 = dpb[3 * 16384 + jb]; \
        pd4 = dpb[4 * 16384 + jb];   pd5 = dpb[5 * 16384 + jb]; \
        pd6 = dpb[6 * 16384 + jb];   pd7 = dpb[7 * 16384 + jb]; \
    }
    #define STOREC() {                                      \
        int rb = t >> 5, cl = t & 31;                       \
        ls[rb][cl] = r0;      ls[8 + rb][cl] = r1;          \
        ls[16 + rb][cl] = r2; ls[24 + rb][cl] = r3;         \
        ls[32 + rb][cl] = r4; ls[40 + rb][cl] = r5;         \
        ls[48 + rb][cl] = r6; ls[56 + rb][cl] = r7;         \
    }
    #define LCC(buf) {                                      \
        float den = ((pd0 + pd1) + (pd2 + pd3)) + ((pd4 + pd5) + (pd6 + pd7)); \
        lc[buf][t] = make_float2(pf2 * LOG2E, -flog2(den)); \
    }

    LOADC(0) LOADP(0)
    STOREC() LCC(0)
    __syncthreads();

    float4v acc0 = {0.f, 0.f, 0.f, 0.f}, acc1 = acc0, acc2 = acc0, acc3 = acc0;

    for (int c = 0; c < 8; c++) {
        int cur = c & 1;
        if (c < 7) { LOADC(c + 1) LOADP(c + 1) }   // in flight during compute

        const short* lsS = (const short*)&ls[0][0];
        const float4* lcf = (const float4*)&lc[cur][0];
        #pragma unroll
        for (int js = 0; js < 8; js++) {
            const float4* cp4 = lcf + js * 16 + q * 4;
            float4 p01 = cp4[0], p23 = cp4[1], p45 = cp4[2], p67 = cp4[3];
            short8 af;
            #define PENT(F2L, LS2, DI)                        \
                {                                             \
                    float t0 = f1L + (F2L);                   \
                    float l2 = fmaxf(t0, 0.2f * t0);          \
                    af[DI] = bf16r(fexp2(l2 + (LS2)));        \
                }
            PENT(p01.x, p01.y, 0) PENT(p01.z, p01.w, 1)
            PENT(p23.x, p23.y, 2) PENT(p23.z, p23.w, 3)
            PENT(p45.x, p45.y, 4) PENT(p45.z, p45.w, 5)
            PENT(p67.x, p67.y, 6) PENT(p67.z, p67.w, 7)
            #undef PENT

            const short* bp = lsS + js * 32 + q * 8;   // + d*264 per row
            short8 b0 = *(const short8*)(bp + (n15 +  0) * 264);
            short8 b1 = *(const short8*)(bp + (n15 + 16) * 264);
            short8 b2 = *(const short8*)(bp + (n15 + 32) * 264);
            short8 b3 = *(const short8*)(bp + (n15 + 48) * 264);

            acc0 = __builtin_amdgcn_mfma_f32_16x16x32_bf16(af, b0, acc0, 0, 0, 0);
            acc1 = __builtin_amdgcn_mfma_f32_16x16x32_bf16(af, b1, acc1, 0, 0, 0);
            acc2 = __builtin_amdgcn_mfma_f32_16x16x32_bf16(af, b2, acc2, 0, 0, 0);
            acc3 = __builtin_amdgcn_mfma_f32_16x16x32_bf16(af, b3, acc3, 0, 0, 0);
        }

        if (c < 7) {
            __syncthreads();          // all waves done reading ls
            STOREC() LCC((c + 1) & 1)
            __syncthreads();          // staged data visible
        }
    }
    #undef LOADC
    #undef LOADP
    #undef STOREC
    #undef LCC

    // D layout: col = n15 (d within 16), row = q*4 + r (i within 16)
    float* ob = out + ((long)b * N + i0 + q * 4) * DF + n15;
    #pragma unroll
    for (int r = 0; r < 4; r++) {
        ob[r * DF + 0]  = eluf(acc0[r]);
        ob[r * DF + 16] = eluf(acc1[r]);
        ob[r * DF + 32] = eluf(acc2[r]);
        ob[r * DF + 48] = eluf(acc3[r]);
    }
}

extern "C" void kernel_launch(void* const* d_in, const int* in_sizes, int n_in,
                              void* d_out, int out_size, void* d_ws, size_t ws_size,
                              hipStream_t stream) {
    const float* h = (const float*)d_in[0];
    const float* W = (const float*)d_in[1];
    const float* a = (const float*)d_in[2];
    float* out = (float*)d_out;

    char* ws = (char*)d_ws;
    const size_t NB = (size_t)B * N;          // 16384 rows
    size_t off = 0;
    short* WTg   = (short*)(ws + off); off += (size_t)KF * DF * sizeof(short); // 32 KB
    float* v12   = (float*)(ws + off); off += 2 * KF * sizeof(float);          // 2 KB
    short* WhT   = (short*)(ws + off); off += NB * DF * sizeof(short);         // 2 MB
    float* f1    = (float*)(ws + off); off += NB * sizeof(float);
    float* f2    = (float*)(ws + off); off += NB * sizeof(float);
    float* dpart = (float*)(ws + off); off += (size_t)IC * NB * sizeof(float); // 512 KB
    (void)off; (void)ws_size;

    k_v<<<65, 256, 0, stream>>>(W, a, WTg, v12);
    k_wh<<<NB / 16, 256, 0, stream>>>(h, WTg, v12, WhT, f1, f2);
    k_denom<<<dim3(N / 256, IC, B), 256, 0, stream>>>(f1, f2, dpart);
    k_attn<<<dim3(N / 64, B), 256, 0, stream>>>(WhT, f1, f2, dpart, out);
}